// Round 2
// baseline (243.263 us; speedup 1.0000x reference)
//
#include <hip/hip_runtime.h>

#define TT 1024
#define BB 4096

// quad_perm DPP: broadcast within 4-lane groups (pure VALU, no LDS)
template<int CTRL>
__device__ __forceinline__ float qperm(float v) {
    int i = __builtin_bit_cast(int, v);
    i = __builtin_amdgcn_mov_dpp(i, CTRL, 0xF, 0xF, true);
    return __builtin_bit_cast(float, i);
}

__global__ void zero_loss_k(float* p) { *p = 0.0f; }

// Pack x bits: xb[e][w] bit i = (x[(32w+i)*BB + e] != 0). Coalesced reads across e.
__global__ void pack_k(const float* __restrict__ x, unsigned* __restrict__ xb) {
    const int gid = blockIdx.x * 256 + threadIdx.x;   // 0 .. BB*32-1
    const int e = gid & (BB - 1);
    const int w = gid >> 12;                          // 0..31
    unsigned m = 0;
    #pragma unroll
    for (int i = 0; i < 32; ++i) {
        float v = x[(size_t)(w * 32 + i) * BB + e];
        m |= (v != 0.0f ? 1u : 0u) << i;
    }
    xb[(size_t)e * 32 + w] = m;
}

// Main sequential kernel: 4 lanes per element (lane j = hidden unit j),
// 16 elements/wave, 256 blocks x 64 threads = 1 wave/CU on all 256 CUs.
// No global loads in the hot loop except 1 word per 32 steps (prefetched).
__launch_bounds__(64, 1)
__global__ void bkt_rnn_k(const unsigned* __restrict__ xb,
                          const float* __restrict__ prior,
                          const float* __restrict__ W_ih,
                          const float* __restrict__ W_hh,
                          const float* __restrict__ b_ih,
                          const float* __restrict__ b_hh,
                          float* __restrict__ out)
{
    const int lane = threadIdx.x;
    const int j    = lane & 3;                      // hidden unit
    const int e    = blockIdx.x * 16 + (lane >> 2); // batch element

    // Fold 2*log2(e) into weights: tanh(z) = 1 - 2/(exp2(z')+1), z' = S*z
    const float S = 2.8853900817779268f;
    // xor-broadcast order: wk multiplies h_{j^k}
    const float w0 = S * W_hh[j * 4 + (j ^ 0)];
    const float w1 = S * W_hh[j * 4 + (j ^ 1)];
    const float w2 = S * W_hh[j * 4 + (j ^ 2)];
    const float w3 = S * W_hh[j * 4 + (j ^ 3)];
    const float bsum = b_ih[j] + b_hh[j];
    const float c0 = S * bsum;             // x == 0
    const float c1 = S * (bsum + W_ih[j]); // x == 1

    float latent = 1.0f / (1.0f + __builtin_amdgcn_exp2f(-1.4426950408889634f * prior[0]));

    const unsigned* bp = xb + (size_t)e * 32;
    float* cOut = out + e;
    float* lOut = out + (size_t)TT * BB + e;

    float hq0 = 0.f, hq1 = 0.f, hq2 = 0.f, hq3 = 0.f;

    unsigned cur = bp[0];
    for (int w = 0; w < 32; ++w) {
        // prefetch next word early; hidden behind 32 steps of compute
        unsigned nxt = bp[(w < 31) ? (w + 1) : 31];
        const int tbase = w * 32;
        #pragma unroll
        for (int i = 0; i < 32; ++i) {
            // off-critical-path: bit select of input contribution
            float cx = (cur & (1u << i)) ? c1 : c0;
            // z tree: 3 dependent hops from hq
            float t1 = fmaf(hq1, w1, cx);
            float t2 = fmaf(hq0, w0, t1);
            float t4 = fmaf(hq2, w2, hq3 * w3);
            float z  = t2 + t4;
            // tanh
            float ex = __builtin_amdgcn_exp2f(z);
            float r  = __builtin_amdgcn_rcpf(ex + 1.0f);
            float h  = fmaf(-2.0f, r, 1.0f);
            // quad broadcast: on lane j, hq_k = h_{j^k}
            hq0 = h;
            hq1 = qperm<0xB1>(h);
            hq2 = qperm<0x4E>(h);
            hq3 = qperm<0x1B>(h);
            // BKT (valid on lane j==0): m_t == latent exactly =>
            //   corr = latent*(1-s-g) + g ; next = latent*(1-f-l) + l
            float gg2  = fmaf(0.5f, hq2, 0.5f);
            float u2   = hq3 + hq2;
            float corr = fmaf(latent, -0.5f * u2, gg2);
            float u1   = hq1 + hq0;
            float nl   = fmaf(0.5f, fmaf(-latent, u1, hq0), 0.5f);
            if (j == 0) {
                cOut[(size_t)(tbase + i) * BB] = corr;
                lOut[(size_t)(tbase + i) * BB] = nl;
            }
            latent = nl;
        }
        cur = nxt;
    }
}

// BCE over stored corrects + y, massively parallel, one atomic per wave.
__global__ void loss_k(const float* __restrict__ corr,
                       const float* __restrict__ y,
                       float* __restrict__ loss)
{
    const size_t N = (size_t)TT * BB;
    float acc = 0.f;
    for (size_t i = blockIdx.x * blockDim.x + threadIdx.x; i < N;
         i += (size_t)gridDim.x * blockDim.x) {
        float c  = corr[i];
        float yv = y[i];
        float lp = (yv != 0.0f) ? c : (1.0f - c);
        float lg = 0.6931471805599453f * __builtin_amdgcn_logf(lp);
        acc += fmaxf(lg, -100.0f);
    }
    #pragma unroll
    for (int o = 32; o >= 1; o >>= 1) acc += __shfl_xor(acc, o, 64);
    if ((threadIdx.x & 63) == 0) {
        atomicAdd(loss, acc * (-1.0f / ((float)TT * (float)BB)));
    }
}

extern "C" void kernel_launch(void* const* d_in, const int* in_sizes, int n_in,
                              void* d_out, int out_size, void* d_ws, size_t ws_size,
                              hipStream_t stream) {
    const float* x    = (const float*)d_in[0];
    const float* y    = (const float*)d_in[1];
    const float* pr   = (const float*)d_in[2];
    const float* W_ih = (const float*)d_in[3];
    const float* W_hh = (const float*)d_in[4];
    const float* b_ih = (const float*)d_in[5];
    const float* b_hh = (const float*)d_in[6];
    float* out = (float*)d_out;
    unsigned* xb = (unsigned*)d_ws;   // BB*32 words = 512 KB

    pack_k<<<BB * 32 / 256, 256, 0, stream>>>(x, xb);
    zero_loss_k<<<1, 1, 0, stream>>>(out + 2 * (size_t)TT * BB);
    bkt_rnn_k<<<BB / 16, 64, 0, stream>>>(xb, pr, W_ih, W_hh, b_ih, b_hh, out);
    loss_k<<<1024, 256, 0, stream>>>(out, y, out + 2 * (size_t)TT * BB);
}

// Round 3
// 170.038 us; speedup vs baseline: 1.4306x; 1.4306x over previous
//
#include <hip/hip_runtime.h>

#define TT 1024
#define BB 4096

// quad_perm DPP broadcast within 4-lane groups
template<int CTRL>
__device__ __forceinline__ float qperm(float v) {
    int i = __builtin_bit_cast(int, v);
    i = __builtin_amdgcn_mov_dpp(i, CTRL, 0xF, 0xF, true);
    return __builtin_bit_cast(float, i);
}

// Pack x bits t-major (xb[e][w], bit i = x[(32w+i)*BB+e]) and y bits transposed
// (ybT[w][e]). Also zeroes the loss accumulator slot.
__global__ void pack_k(const float* __restrict__ x, const float* __restrict__ y,
                       unsigned* __restrict__ xb, unsigned* __restrict__ ybT,
                       float* __restrict__ loss) {
    const int gid = blockIdx.x * 256 + threadIdx.x;   // 0 .. BB*32-1
    const int e = gid & (BB - 1);
    const int w = gid >> 12;                          // 0..31
    unsigned mx = 0, my = 0;
    #pragma unroll
    for (int i = 0; i < 32; ++i) {
        mx |= (x[(size_t)(w * 32 + i) * BB + e] != 0.0f ? 1u : 0u) << i;
        my |= (y[(size_t)(w * 32 + i) * BB + e] != 0.0f ? 1u : 0u) << i;
    }
    xb[e * 32 + w] = mx;
    ybT[w * BB + e] = my;
    if (gid == 0) *loss = 0.0f;
}

// 4 lanes/element (lane j = hidden unit j), 16 elements/wave, 256 single-wave
// blocks. State carried as r = 1/(exp2(z')+1) (h = 1-2r, params p = 1-r).
// Outputs buffered 32 steps in LDS, flushed with coalesced dwordx4; BCE done
// during flush by all 64 lanes.
__launch_bounds__(64, 1)
__global__ void bkt_rnn_k(const unsigned* __restrict__ xb,
                          const unsigned* __restrict__ ybT,
                          const float* __restrict__ prior,
                          const float* __restrict__ W_ih,
                          const float* __restrict__ W_hh,
                          const float* __restrict__ b_ih,
                          const float* __restrict__ b_hh,
                          float* __restrict__ out)
{
    __shared__ float cbuf[512];  // [i][le] corr
    __shared__ float nbuf[512];  // [i][le] next_latent
    const int lane = threadIdx.x;
    const int j  = lane & 3;       // hidden unit (sequential phase)
    const int le = lane >> 2;      // local element (sequential phase)
    const int e0 = blockIdx.x * 16;
    const int e  = e0 + le;
    const int rr = lane >> 2;      // flush row 0..15
    const int cc = lane & 3;       // flush chunk 0..3

    const float S = 2.8853900817779268f;  // 2*log2(e)
    // xor-broadcast order; r-form weights: z' = base + sum vk*rq_k
    const float wj0 = W_hh[j * 4 + (j ^ 0)];
    const float wj1 = W_hh[j * 4 + (j ^ 1)];
    const float wj2 = W_hh[j * 4 + (j ^ 2)];
    const float wj3 = W_hh[j * 4 + (j ^ 3)];
    const float v0 = -2.f * S * wj0, v1 = -2.f * S * wj1;
    const float v2 = -2.f * S * wj2, v3 = -2.f * S * wj3;
    const float base0 = S * (b_ih[j] + b_hh[j] + wj0 + wj1 + wj2 + wj3);
    const float base1 = base0 + S * W_ih[j];

    float latent = 1.0f / (1.0f + __builtin_amdgcn_exp2f(-1.4426950408889634f * prior[0]));
    float rq0 = 0.5f, rq1 = 0.5f, rq2 = 0.5f, rq3 = 0.5f;  // h=0 -> r=0.5
    float lossAcc = 0.0f;

    const unsigned* xp = xb + e * 32;
    unsigned curx = xp[0];

    for (int w = 0; w < 32; ++w) {
        unsigned nxtx = xp[(w < 31) ? (w + 1) : 31];
        uint4 yw4 = *(const uint4*)&ybT[w * BB + e0 + cc * 4];

        #pragma unroll
        for (int i = 0; i < 32; ++i) {
            float cxb = (curx & (1u << i)) ? base1 : base0;
            // z' tree: 3 dependent hops from rq*
            float m  = rq2 * v2;
            float a  = fmaf(rq0, v0, cxb);
            float b_ = fmaf(rq1, v1, m);
            float c_ = fmaf(rq3, v3, a);
            float z  = b_ + c_;
            float ex = __builtin_amdgcn_exp2f(z);
            float r  = __builtin_amdgcn_rcpf(ex + 1.0f);
            rq0 = r;
            rq1 = qperm<0xB1>(r);
            rq2 = qperm<0x4E>(r);
            rq3 = qperm<0x1B>(r);
            // valid on lane j==0 (rq_k = r_k): params p = 1 - r
            //   corr = latent*(r_g+r_s-1) + (1-r_g);  nl = latent*(r_l+r_f-1) + (1-r_l)
            float corr = fmaf(latent, (rq2 + rq3) - 1.0f, 1.0f - rq2);
            float nl   = fmaf(latent, (rq0 + rq1) - 1.0f, 1.0f - rq0);
            if (j == 0) { cbuf[i * 16 + le] = corr; nbuf[i * 16 + le] = nl; }
            latent = nl;
        }
        __syncthreads();  // single-wave block: ordering only
        float4 c0 = *(const float4*)&cbuf[rr * 16 + cc * 4];
        float4 c1 = *(const float4*)&cbuf[(rr + 16) * 16 + cc * 4];
        float4 n0 = *(const float4*)&nbuf[rr * 16 + cc * 4];
        float4 n1 = *(const float4*)&nbuf[(rr + 16) * 16 + cc * 4];
        __syncthreads();

        const size_t tb = (size_t)w * 32;
        float* cO = out + (tb + rr) * BB + e0 + cc * 4;
        *(float4*)cO = c0;
        *(float4*)(cO + (size_t)16 * BB) = c1;
        float* lO = cO + (size_t)TT * BB;
        *(float4*)lO = n0;
        *(float4*)(lO + (size_t)16 * BB) = n1;

        // BCE for this 32x16 block, split across all 64 lanes (8 each)
        auto bce = [&](float c, unsigned wbits, int bit) {
            float lp = ((wbits >> bit) & 1u) ? c : (1.0f - c);
            float lg = __builtin_amdgcn_logf(lp) * 0.6931471805599453f;
            lossAcc += fmaxf(lg, -100.0f);
        };
        bce(c0.x, yw4.x, rr);      bce(c0.y, yw4.y, rr);
        bce(c0.z, yw4.z, rr);      bce(c0.w, yw4.w, rr);
        bce(c1.x, yw4.x, rr + 16); bce(c1.y, yw4.y, rr + 16);
        bce(c1.z, yw4.z, rr + 16); bce(c1.w, yw4.w, rr + 16);

        curx = nxtx;
    }

    #pragma unroll
    for (int o = 32; o >= 1; o >>= 1) lossAcc += __shfl_xor(lossAcc, o, 64);
    if (lane == 0) {
        atomicAdd(out + 2 * (size_t)TT * BB, lossAcc * (-1.0f / ((float)TT * (float)BB)));
    }
}

extern "C" void kernel_launch(void* const* d_in, const int* in_sizes, int n_in,
                              void* d_out, int out_size, void* d_ws, size_t ws_size,
                              hipStream_t stream) {
    const float* x    = (const float*)d_in[0];
    const float* y    = (const float*)d_in[1];
    const float* pr   = (const float*)d_in[2];
    const float* W_ih = (const float*)d_in[3];
    const float* W_hh = (const float*)d_in[4];
    const float* b_ih = (const float*)d_in[5];
    const float* b_hh = (const float*)d_in[6];
    float* out = (float*)d_out;
    unsigned* xb  = (unsigned*)d_ws;                    // BB*32 words
    unsigned* ybT = (unsigned*)d_ws + (size_t)BB * 32;  // BB*32 words

    pack_k<<<BB * 32 / 256, 256, 0, stream>>>(x, y, xb, ybT, out + 2 * (size_t)TT * BB);
    bkt_rnn_k<<<BB / 16, 64, 0, stream>>>(xb, ybT, pr, W_ih, W_hh, b_ih, b_hh, out);
}

// Round 4
// 140.720 us; speedup vs baseline: 1.7287x; 1.2083x over previous
//
#include <hip/hip_runtime.h>

#define TT 1024
#define BB 4096
#define CHUNK 128     // output steps per chunk
#define WARM 320      // max warmup steps
#define NC (TT / CHUNK)

// quad_perm DPP broadcast within 4-lane groups
template<int CTRL>
__device__ __forceinline__ float qperm(float v) {
    int i = __builtin_bit_cast(int, v);
    i = __builtin_amdgcn_mov_dpp(i, CTRL, 0xF, 0xF, true);
    return __builtin_bit_cast(float, i);
}

// Block = 1 wave (64 thr) handles 16 elements x 1 time-chunk.
// Grid = 256 e-groups x 8 chunks = 2048 blocks (c = blockIdx >> 8 so adjacent
// blocks stream consecutive e-ranges of the same x window).
// Lane j = lane&3 owns hidden unit j; state r = 1/(exp2(z')+1), p = 1-r.
__launch_bounds__(64, 2)
__global__ void bkt_rnn_k(const float* __restrict__ x,
                          const float* __restrict__ y,
                          const float* __restrict__ prior,
                          const float* __restrict__ W_ih,
                          const float* __restrict__ W_hh,
                          const float* __restrict__ b_ih,
                          const float* __restrict__ b_hh,
                          float* __restrict__ out,
                          float* __restrict__ lossPart)
{
    __shared__ unsigned char xls[(WARM + CHUNK) * 16]; // x bits, [s][le]
    __shared__ unsigned char yls[CHUNK * 16];          // y bits, [i][le]
    __shared__ float cbuf[512];                        // flush: [i][le] corr
    __shared__ float nbuf[512];                        // flush: [i][le] next_latent

    const int lane = threadIdx.x;
    const int j  = lane & 3;
    const int le = lane >> 2;
    const int c  = blockIdx.x >> 8;         // chunk 0..7
    const int eg = blockIdx.x & 255;        // element group
    const int e0 = eg * 16;

    const int t_out0   = c * CHUNK;
    const int t_start  = (t_out0 > WARM) ? (t_out0 - WARM) : 0;
    const int nwarm    = t_out0 - t_start;
    const int nsteps   = nwarm + CHUNK;

    // ---- prologue: stage x (whole window) and y (output window) as LDS bytes
    for (int idx = lane; idx < nsteps * 16; idx += 64) {
        int t = t_start + (idx >> 4);
        xls[idx] = (x[(size_t)t * BB + e0 + (idx & 15)] != 0.0f);
    }
    for (int idx = lane; idx < CHUNK * 16; idx += 64) {
        int t = t_out0 + (idx >> 4);
        yls[idx] = (y[(size_t)t * BB + e0 + (idx & 15)] != 0.0f);
    }
    __syncthreads();

    // ---- constants (r-form, 2*log2e folded)
    const float S = 2.8853900817779268f;
    const float wj0 = W_hh[j * 4 + (j ^ 0)];
    const float wj1 = W_hh[j * 4 + (j ^ 1)];
    const float wj2 = W_hh[j * 4 + (j ^ 2)];
    const float wj3 = W_hh[j * 4 + (j ^ 3)];
    const float v0 = -2.f * S * wj0, v1 = -2.f * S * wj1;
    const float v2 = -2.f * S * wj2, v3 = -2.f * S * wj3;
    const float base0 = S * (b_ih[j] + b_hh[j] + wj0 + wj1 + wj2 + wj3);
    const float base1 = base0 + S * W_ih[j];

    float latent = 1.0f / (1.0f + __builtin_amdgcn_exp2f(-1.4426950408889634f * prior[0]));
    float rq0 = 0.5f, rq1 = 0.5f, rq2 = 0.5f, rq3 = 0.5f; // h=0
    float lossAcc = 0.0f;

    // ---- warmup: h-RNN + latent only (no outputs, no BCE)
    #pragma unroll 8
    for (int s = 0; s < nwarm; ++s) {
        float cxb = xls[(s << 4) | le] ? base1 : base0;
        float z = fmaf(rq0, v0, cxb);
        z = fmaf(rq1, v1, z);
        z = fmaf(rq2, v2, z);
        z = fmaf(rq3, v3, z);
        float ex = __builtin_amdgcn_exp2f(z);
        float r  = __builtin_amdgcn_rcpf(ex + 1.0f);
        rq0 = r;
        rq1 = qperm<0xB1>(r);
        rq2 = qperm<0x4E>(r);
        rq3 = qperm<0x1B>(r);
        float u1 = rq0 + rq1;
        latent = fmaf(latent, u1 - 1.0f, 1.0f - rq0);
    }

    // ---- output phase: 4 groups of 32 steps, LDS-buffered flush
    const int rr = lane >> 2;   // flush row
    const int cc = lane & 3;    // flush chunk-of-4
    for (int g = 0; g < 4; ++g) {
        const int sbase = nwarm + g * 32;
        #pragma unroll
        for (int i = 0; i < 32; ++i) {
            float cxb = xls[((sbase + i) << 4) | le] ? base1 : base0;
            float z = fmaf(rq0, v0, cxb);
            z = fmaf(rq1, v1, z);
            z = fmaf(rq2, v2, z);
            z = fmaf(rq3, v3, z);
            float ex = __builtin_amdgcn_exp2f(z);
            float r  = __builtin_amdgcn_rcpf(ex + 1.0f);
            rq0 = r;
            rq1 = qperm<0xB1>(r);
            rq2 = qperm<0x4E>(r);
            rq3 = qperm<0x1B>(r);
            float u2   = rq2 + rq3;
            float corr = fmaf(latent, u2 - 1.0f, 1.0f - rq2);
            float u1   = rq0 + rq1;
            float nl   = fmaf(latent, u1 - 1.0f, 1.0f - rq0);
            if (j == 0) { cbuf[i * 16 + le] = corr; nbuf[i * 16 + le] = nl; }
            latent = nl;
        }
        __syncthreads();
        float4 c0 = *(const float4*)&cbuf[rr * 16 + cc * 4];
        float4 c1 = *(const float4*)&cbuf[(rr + 16) * 16 + cc * 4];
        float4 n0 = *(const float4*)&nbuf[rr * 16 + cc * 4];
        float4 n1 = *(const float4*)&nbuf[(rr + 16) * 16 + cc * 4];
        __syncthreads();

        const int tg = t_out0 + g * 32;
        float* cO = out + (size_t)(tg + rr) * BB + e0 + cc * 4;
        *(float4*)cO = c0;
        *(float4*)(cO + (size_t)16 * BB) = c1;
        float* lO = cO + (size_t)TT * BB;
        *(float4*)lO = n0;
        *(float4*)(lO + (size_t)16 * BB) = n1;

        // BCE for this 32x16 block across all 64 lanes (8 each), y from LDS
        auto bce = [&](float cv, int i, int el) {
            float lp = yls[((g * 32 + i) << 4) | el] ? cv : (1.0f - cv);
            float lg = __builtin_amdgcn_logf(lp) * 0.6931471805599453f;
            lossAcc += fmaxf(lg, -100.0f);
        };
        bce(c0.x, rr,      cc * 4 + 0); bce(c0.y, rr,      cc * 4 + 1);
        bce(c0.z, rr,      cc * 4 + 2); bce(c0.w, rr,      cc * 4 + 3);
        bce(c1.x, rr + 16, cc * 4 + 0); bce(c1.y, rr + 16, cc * 4 + 1);
        bce(c1.z, rr + 16, cc * 4 + 2); bce(c1.w, rr + 16, cc * 4 + 3);
    }

    #pragma unroll
    for (int o = 32; o >= 1; o >>= 1) lossAcc += __shfl_xor(lossAcc, o, 64);
    if (lane == 0) lossPart[blockIdx.x] = lossAcc;
}

// Reduce 2048 per-block partials -> final mean NLL
__global__ void reduce_k(const float* __restrict__ part, float* __restrict__ loss) {
    float acc = 0.f;
    for (int i = threadIdx.x; i < 2048; i += 256) acc += part[i];
    #pragma unroll
    for (int o = 32; o >= 1; o >>= 1) acc += __shfl_xor(acc, o, 64);
    __shared__ float w[4];
    if ((threadIdx.x & 63) == 0) w[threadIdx.x >> 6] = acc;
    __syncthreads();
    if (threadIdx.x == 0) {
        float t = w[0] + w[1] + w[2] + w[3];
        *loss = t * (-1.0f / ((float)TT * (float)BB));
    }
}

extern "C" void kernel_launch(void* const* d_in, const int* in_sizes, int n_in,
                              void* d_out, int out_size, void* d_ws, size_t ws_size,
                              hipStream_t stream) {
    const float* x    = (const float*)d_in[0];
    const float* y    = (const float*)d_in[1];
    const float* pr   = (const float*)d_in[2];
    const float* W_ih = (const float*)d_in[3];
    const float* W_hh = (const float*)d_in[4];
    const float* b_ih = (const float*)d_in[5];
    const float* b_hh = (const float*)d_in[6];
    float* out = (float*)d_out;
    float* lossPart = (float*)d_ws;  // 2048 floats

    bkt_rnn_k<<<256 * NC, 64, 0, stream>>>(x, y, pr, W_ih, W_hh, b_ih, b_hh, out, lossPart);
    reduce_k<<<1, 256, 0, stream>>>(lossPart, out + 2 * (size_t)TT * BB);
}